// Round 3
// baseline (481.821 us; speedup 1.0000x reference)
//
#include <hip/hip_runtime.h>

#define Bn 4
#define Cn 256
#define Tn 4096

typedef unsigned short u16;
typedef __bf16 bf16x8 __attribute__((ext_vector_type(8)));
typedef float f32x4 __attribute__((ext_vector_type(4)));
typedef u16 u16x8 __attribute__((ext_vector_type(8)));

__device__ __forceinline__ float b2f(u16 u) {
    union { unsigned int i; float f; } v;
    v.i = ((unsigned int)u) << 16;
    return v.f;
}
__device__ __forceinline__ u16 f2b(float f) {
    union { float f; unsigned int i; } v;
    v.f = f;
    unsigned int r = v.i + 0x7FFFu + ((v.i >> 16) & 1u);
    return (u16)(r >> 16);
}

// ---------------------------------------------------------------------------
// Weight convert: five fp32 [C][C] weights -> contiguous bf16 regions in ws.
// 320 blocks x 256 thr x 4 elems. 65536 % 4 == 0 so float4 never crosses
// a region boundary.
// ---------------------------------------------------------------------------
__global__ __launch_bounds__(256) void cvt_kernel(
    const float* __restrict__ w0, const float* __restrict__ w1,
    const float* __restrict__ w2, const float* __restrict__ w3,
    const float* __restrict__ w4, u16* __restrict__ dst)
{
    int gid = blockIdx.x * 256 + threadIdx.x;
    int base = gid * 4;
    int region = base >> 16;
    int off = base & 65535;
    const float* src = region == 0 ? w0 : region == 1 ? w1
                     : region == 2 ? w2 : region == 3 ? w3 : w4;
    float4 v = *(const float4*)(src + off);
    ushort4 o;
    o.x = f2b(v.x); o.y = f2b(v.y); o.z = f2b(v.z); o.w = f2b(v.w);
    *(ushort4*)(dst + base) = o;
}

// ---------------------------------------------------------------------------
// LN kernel: h = x*m (f32 stats), ln = (h-mu)*rsqrt(var+eps)*gamma+beta,
// written transposed as lnT [B][T][C] bf16. x fp32 [B][C][T].
// ---------------------------------------------------------------------------
__global__ __launch_bounds__(256) void ln_kernel(
    const float* __restrict__ x, const float* __restrict__ mask,
    const float* __restrict__ gamma, const float* __restrict__ beta,
    u16* __restrict__ lnT)
{
    __shared__ __attribute__((aligned(16))) u16 tile[64][264];  // [t][c], bf16 h
    __shared__ float ssum[4][64], ssq[4][64], smu[64], srs[64];
    const int tid = threadIdx.x;
    const int b = blockIdx.y;
    const int t0 = blockIdx.x * 64;
    const int g = tid >> 6, tl = tid & 63;
    const int t = t0 + tl;
    const float mval = mask[b * Tn + t];
    float s = 0.f, s2 = 0.f;
    for (int c = g; c < Cn; c += 4) {
        float v = x[((size_t)(b * Cn + c)) * Tn + t] * mval;
        s += v; s2 += v * v;
        tile[tl][c] = f2b(v);
    }
    ssum[g][tl] = s; ssq[g][tl] = s2;
    __syncthreads();
    if (tid < 64) {
        float su = ssum[0][tid] + ssum[1][tid] + ssum[2][tid] + ssum[3][tid];
        float sq = ssq[0][tid] + ssq[1][tid] + ssq[2][tid] + ssq[3][tid];
        float mu = su * (1.f / Cn);
        float var = sq * (1.f / Cn) - mu * mu;
        var = fmaxf(var, 0.0f);
        smu[tid] = mu;
        srs[tid] = 1.0f / sqrtf(var + 1e-5f);
    }
    __syncthreads();
    for (int it = 0; it < 8; it++) {
        int idx = it * 256 + tid;
        int row = idx >> 5, c16 = idx & 31;
        float mu = smu[row], rs = srs[row];
        u16x8 ov;
        for (int j = 0; j < 8; j++) {
            int c = c16 * 8 + j;
            float h = b2f(tile[row][c]);
            float v = (h - mu) * rs * gamma[c] + beta[c];
            ov[j] = f2b(v);
        }
        *(u16x8*)(lnT + ((size_t)(b * Tn + t0 + row)) * Cn + c16 * 8) = ov;
    }
}

// ---------------------------------------------------------------------------
// GEMM: C[m,n] = sum_k A[m,k]*B[n,k]  (both operands bf16, k-contiguous)
// ORIENT2=false: A = X rows (m=t), B = Wbf rows (n=o), out Y[t][o] bf16,
//                epilogue (acc+bias[o])*mask[t]
// ORIENT2=true : A = Wbf rows (m=o), B = X rows (n=t), out Y[o][t] bf16;
//                FINAL: fp32 out, (xres + val*m)*m
// Block tile 128x128, BK=64 staged, wave tile 64x64 (4x4 MFMA accum).
// ---------------------------------------------------------------------------
template<bool ORIENT2, bool FINAL>
__global__ __launch_bounds__(256) void gemm_kernel(
    const u16* __restrict__ Xb,
    const u16* __restrict__ Wb,
    const float* __restrict__ bias,
    const float* __restrict__ mask,
    const float* __restrict__ xres,
    u16* __restrict__ Yout,
    float* __restrict__ YoutF)
{
    __shared__ __attribute__((aligned(16))) u16 Al[128][72];
    __shared__ __attribute__((aligned(16))) u16 Bl[128][72];
    const int tid = threadIdx.x;
    const int b = blockIdx.z;
    const int m0 = blockIdx.x * 128;
    const int n0 = blockIdx.y * 128;
    const int wave = tid >> 6, lane = tid & 63;
    const int ln16 = lane & 15, quad = lane >> 4;
    const int wm = (wave & 1) * 64, wn = (wave >> 1) * 64;

    const u16* Abase = ORIENT2 ? (Wb + (size_t)m0 * Cn)
                               : (Xb + ((size_t)(b * Tn + m0)) * Cn);
    const u16* Bbase = ORIENT2 ? (Xb + ((size_t)(b * Tn + n0)) * Cn)
                               : (Wb + (size_t)n0 * Cn);

    f32x4 acc[4][4];
    for (int i = 0; i < 4; i++)
        for (int j = 0; j < 4; j++) acc[i][j] = (f32x4){0.f, 0.f, 0.f, 0.f};

    for (int k0 = 0; k0 < Cn; k0 += 64) {
        for (int it = 0; it < 4; it++) {
            int idx = it * 256 + tid;
            int row = idx >> 3, c16 = idx & 7;
            *(uint4*)(&Al[row][c16 * 8]) =
                *(const uint4*)(Abase + (size_t)row * Cn + k0 + c16 * 8);
            *(uint4*)(&Bl[row][c16 * 8]) =
                *(const uint4*)(Bbase + (size_t)row * Cn + k0 + c16 * 8);
        }
        __syncthreads();
        for (int kk = 0; kk < 2; kk++) {
            bf16x8 af[4], bfr[4];
            for (int i = 0; i < 4; i++)
                af[i] = *(const bf16x8*)(&Al[wm + i * 16 + ln16][kk * 32 + quad * 8]);
            for (int j = 0; j < 4; j++)
                bfr[j] = *(const bf16x8*)(&Bl[wn + j * 16 + ln16][kk * 32 + quad * 8]);
            for (int i = 0; i < 4; i++)
                for (int j = 0; j < 4; j++)
                    acc[i][j] = __builtin_amdgcn_mfma_f32_16x16x32_bf16(
                        af[i], bfr[j], acc[i][j], 0, 0, 0);
        }
        __syncthreads();
    }
    for (int i = 0; i < 4; i++) {
        for (int j = 0; j < 4; j++) {
            int mm = m0 + wm + i * 16 + quad * 4;
            int nn = n0 + wn + j * 16 + ln16;
            for (int r = 0; r < 4; r++) {
                int m = mm + r;
                float val = acc[i][j][r];
                if (!ORIENT2) {
                    int tt = m, oo = nn;
                    val += bias[oo];
                    val *= mask[b * Tn + tt];
                    Yout[((size_t)(b * Tn + tt)) * Cn + oo] = f2b(val);
                } else {
                    int oo = m, tt = nn;
                    val += bias[oo];
                    float mk = mask[b * Tn + tt];
                    if (FINAL) {
                        float xr = xres[((size_t)(b * Cn + oo)) * Tn + tt];
                        YoutF[((size_t)(b * Cn + oo)) * Tn + tt] = (xr + val * mk) * mk;
                    } else {
                        Yout[((size_t)(b * Cn + oo)) * Tn + tt] = f2b(val * mk);
                    }
                }
            }
        }
    }
}

// ---------------------------------------------------------------------------
// Flash attention: one block = 64 q rows (4 waves x 16 rows), s tiles of 32.
// qT/kT [B][T][C] bf16, v [B][C][T] bf16, mask fp32. Online softmax state
// replicated across the 16 col-lanes of each row; no infinities anywhere.
// P converts C-layout -> A-layout via per-wave LDS round-trip (DS pipe is
// in-order within a wave).
// ---------------------------------------------------------------------------
__global__ __launch_bounds__(256) void attn_kernel(
    const u16* __restrict__ qT, const u16* __restrict__ kT,
    const u16* __restrict__ vv, const float* __restrict__ mask,
    u16* __restrict__ h2T)
{
    __shared__ __attribute__((aligned(16))) u16 kls[32][264];    // [s][c]
    __shared__ __attribute__((aligned(16))) u16 vls[256][40];    // [c][s]
    __shared__ __attribute__((aligned(16))) u16 pls[4][16][40];  // per-wave P [t][s]
    const int tid = threadIdx.x;
    const int b = blockIdx.x & 3;          // batch->XCD pinning for K/V L2 reuse
    const int t0 = (blockIdx.x >> 2) * 64;
    const int wave = tid >> 6, lane = tid & 63;
    const int ln16 = lane & 15, quad = lane >> 4;

    bf16x8 qf[8];
    {
        const u16* qb = qT + ((size_t)(b * Tn + t0 + wave * 16 + ln16)) * Cn + quad * 8;
        for (int kk = 0; kk < 8; kk++) qf[kk] = *(const bf16x8*)(qb + kk * 32);
    }
    f32x4 acc[16];
    for (int i = 0; i < 16; i++) acc[i] = (f32x4){0.f, 0.f, 0.f, 0.f};
    float mi[4], li[4];
    for (int r = 0; r < 4; r++) { mi[r] = -1e30f; li[r] = 0.f; }

    for (int s0 = 0; s0 < Tn; s0 += 32) {
        for (int it = 0; it < 4; it++) {           // K tile [32][256]
            int idx = it * 256 + tid;
            int row = idx >> 5, c16 = idx & 31;
            *(uint4*)(&kls[row][c16 * 8]) =
                *(const uint4*)(kT + ((size_t)(b * Tn + s0 + row)) * Cn + c16 * 8);
        }
        for (int it = 0; it < 4; it++) {           // V tile [256][32]
            int idx = it * 256 + tid;
            int row = idx >> 2, s16 = idx & 3;
            *(uint4*)(&vls[row][s16 * 8]) =
                *(const uint4*)(vv + ((size_t)(b * Cn + row)) * Tn + s0 + s16 * 8);
        }
        float negk[2];
        for (int j = 0; j < 2; j++)
            negk[j] = (1.0f - mask[b * Tn + s0 + j * 16 + ln16]) * -1e8f;
        __syncthreads();

        f32x4 S[2];
        S[0] = (f32x4){0.f, 0.f, 0.f, 0.f};
        S[1] = S[0];
        for (int kk = 0; kk < 8; kk++) {
            for (int j = 0; j < 2; j++) {
                bf16x8 bf = *(const bf16x8*)(&kls[j * 16 + ln16][kk * 32 + quad * 8]);
                S[j] = __builtin_amdgcn_mfma_f32_16x16x32_bf16(qf[kk], bf, S[j], 0, 0, 0);
            }
        }
        float alpha[4];
        for (int r = 0; r < 4; r++) {
            float s0v = S[0][r] * 0.0625f + negk[0];
            float s1v = S[1][r] * 0.0625f + negk[1];
            float mx = fmaxf(s0v, s1v);
            mx = fmaxf(mx, __shfl_xor(mx, 1));
            mx = fmaxf(mx, __shfl_xor(mx, 2));
            mx = fmaxf(mx, __shfl_xor(mx, 4));
            mx = fmaxf(mx, __shfl_xor(mx, 8));
            float mn = fmaxf(mi[r], mx);
            float al = __expf(mi[r] - mn);
            float p0 = __expf(s0v - mn);
            float p1 = __expf(s1v - mn);
            S[0][r] = p0; S[1][r] = p1;
            float rs = p0 + p1;
            rs += __shfl_xor(rs, 1);
            rs += __shfl_xor(rs, 2);
            rs += __shfl_xor(rs, 4);
            rs += __shfl_xor(rs, 8);
            li[r] = li[r] * al + rs;
            mi[r] = mn;
            alpha[r] = al;
        }
        for (int i = 0; i < 16; i++)
            for (int r = 0; r < 4; r++) acc[i][r] *= alpha[r];
        // P: C-layout -> LDS [t][s]
        for (int j = 0; j < 2; j++)
            for (int r = 0; r < 4; r++)
                pls[wave][quad * 4 + r][j * 16 + ln16] = f2b(S[j][r]);
        // PV: one k=32 MFMA step; B-frag = v[c][s] directly s-contiguous
        {
            bf16x8 pf = *(const bf16x8*)(&pls[wave][ln16][quad * 8]);
            for (int ct = 0; ct < 16; ct++) {
                bf16x8 vf = *(const bf16x8*)(&vls[ct * 16 + ln16][quad * 8]);
                acc[ct] = __builtin_amdgcn_mfma_f32_16x16x32_bf16(pf, vf, acc[ct], 0, 0, 0);
            }
        }
        __syncthreads();
    }
    for (int ct = 0; ct < 16; ct++) {
        for (int r = 0; r < 4; r++) {
            int t = t0 + wave * 16 + quad * 4 + r;
            float li_safe = (li[r] > 0.f) ? li[r] : 1.0f;
            float val = acc[ct][r] / li_safe;
            h2T[((size_t)(b * Tn + t)) * Cn + ct * 16 + ln16] = f2b(val);
        }
    }
}

extern "C" void kernel_launch(void* const* d_in, const int* in_sizes, int n_in,
                              void* d_out, int out_size, void* d_ws, size_t ws_size,
                              hipStream_t stream)
{
    const float* x     = (const float*)d_in[0];
    const float* xmask = (const float*)d_in[1];
    const float* gamma = (const float*)d_in[2];
    const float* beta  = (const float*)d_in[3];
    const float* Wp = (const float*)d_in[4];
    const float* bp = (const float*)d_in[5];
    const float* Wq = (const float*)d_in[6];
    const float* bq = (const float*)d_in[7];
    const float* Wk = (const float*)d_in[8];
    const float* bk = (const float*)d_in[9];
    const float* Wv = (const float*)d_in[10];
    const float* bv = (const float*)d_in[11];
    const float* Wo = (const float*)d_in[12];
    const float* bo = (const float*)d_in[13];
    float* out = (float*)d_out;

    // ws: 5 activation slots (8 MB bf16 each) + 5 bf16 weights (640 KB)
    u16* ws = (u16*)d_ws;
    const size_t SZ = (size_t)Bn * Tn * Cn;  // 4M elems
    u16* lnT = ws;            // [B][T][C]
    u16* h1T = ws + SZ;       // [B][T][C]
    u16* qTt = ws + 2 * SZ;   // [B][T][C]
    u16* kTt = ws + 3 * SZ;   // [B][T][C]
    u16* vB  = ws + 4 * SZ;   // [B][C][T]
    u16* h2T = ws;            // [B][T][C] (reuse slot 0; lnT dead after Wp GEMM)
    u16* wbf = ws + 5 * SZ;   // 5 x 65536 bf16 weights: Wp,Wq,Wk,Wv,Wo

    const size_t WSZ = (size_t)Cn * Cn;
    u16* WpB = wbf;
    u16* WqB = wbf + WSZ;
    u16* WkB = wbf + 2 * WSZ;
    u16* WvB = wbf + 3 * WSZ;
    u16* WoB = wbf + 4 * WSZ;

    dim3 blk(256);
    cvt_kernel<<<dim3(320), blk, 0, stream>>>(Wp, Wq, Wk, Wv, Wo, wbf);
    ln_kernel<<<dim3(Tn / 64, Bn), blk, 0, stream>>>(x, xmask, gamma, beta, lnT);
    gemm_kernel<false, false><<<dim3(Tn / 128, Cn / 128, Bn), blk, 0, stream>>>(
        lnT, WpB, bp, xmask, nullptr, h1T, nullptr);
    gemm_kernel<false, false><<<dim3(Tn / 128, Cn / 128, Bn), blk, 0, stream>>>(
        h1T, WqB, bq, xmask, nullptr, qTt, nullptr);
    gemm_kernel<false, false><<<dim3(Tn / 128, Cn / 128, Bn), blk, 0, stream>>>(
        h1T, WkB, bk, xmask, nullptr, kTt, nullptr);
    gemm_kernel<true, false><<<dim3(Cn / 128, Tn / 128, Bn), blk, 0, stream>>>(
        h1T, WvB, bv, xmask, nullptr, vB, nullptr);
    attn_kernel<<<dim3(Bn * Tn / 64), blk, 0, stream>>>(qTt, kTt, vB, xmask, h2T);
    gemm_kernel<true, true><<<dim3(Cn / 128, Tn / 128, Bn), blk, 0, stream>>>(
        h2T, WoB, bo, xmask, x, nullptr, out);
}